// Round 18
// baseline (165.142 us; speedup 1.0000x reference)
//
#include <hip/hip_runtime.h>
#include <hip/hip_bf16.h>

#define NB 31
#define PD 64

typedef __attribute__((ext_vector_type(2))) float f32x2;
typedef __attribute__((ext_vector_type(8))) short short8;
typedef __attribute__((ext_vector_type(16))) float f32x16;
typedef __attribute__((ext_vector_type(8))) int int8v;

// scalar GELU (fuse kernel): x * clamp(0.5 + x*(a + b x^2 + c x^4), 0, 1)
__device__ __forceinline__ float gelu_f(float x) {
    float y = x * x;
    float p = __builtin_fmaf(y, __builtin_fmaf(y, 0.0042294f, -0.056913f), 0.395442f);
    float phi;
    asm("v_fma_f32 %0, %1, %2, 0.5 clamp" : "=v"(phi) : "v"(x), "v"(p));
    return x * phi;
}

// packed GELU: 2 elements via v_pk_* f32 (LLVM emits packed ops for <2 x float>)
__device__ __forceinline__ f32x2 gelu2(f32x2 x) {
    f32x2 y = x * x;
    f32x2 t = y * (f32x2)(0.0042294f) + (f32x2)(-0.056913f);   // contracts to pk_fma
    f32x2 p = y * t + (f32x2)(0.395442f);
    f32x2 phi = x * p + (f32x2)(0.5f);
    phi = __builtin_elementwise_max(phi, (f32x2)(0.0f));
    phi = __builtin_elementwise_min(phi, (f32x2)(1.0f));
    return x * phi;
}

__device__ __forceinline__ unsigned int cvt_pk_bf16(float lo, float hi) {
    unsigned int r;
    asm("v_cvt_pk_bf16_f32 %0, %1, %2" : "=v"(r) : "v"(lo), "v"(hi));
    return r;
}

// 2 floats -> 2 fp8 e4m3 bytes in bits [15:0] (old=0 => high bits 0)
__device__ __forceinline__ unsigned int pk_fp8(float a, float b) {
    return (unsigned int)__builtin_amdgcn_cvt_pk_fp8_f32(a, b, 0, false);
}

__device__ __forceinline__ int8v mk8(uint4 a, uint4 b) {
    int8v r;
    r[0] = a.x; r[1] = a.y; r[2] = a.z; r[3] = a.w;
    r[4] = b.x; r[5] = b.y; r[6] = b.z; r[7] = b.w;
    return r;
}

// W2 (OIHW fp32) -> fp8 MX-MFMA A-fragments for 32x32x64, byte-permuted to
// match h1's layout (r13-verified): A-frag byte bb (0..31) holds ic_local32 =
// 8*((bb>>2)&3) + 4*(bb>>4) + (bb&3); dwords out = {d0,d2,d4,d6, d1,d3,d5,d7}.
// W2s[gh][tap][lane] = 32 bytes; gh = g*2+oh; lane = hi*32 + col (col = oc&31).
__global__ void prep_w2(const float* __restrict__ W2, unsigned char* __restrict__ W2s) {
    int e = blockIdx.x * 256 + threadIdx.x;
    const int TOT = NB * 2 * 9 * 64;
    if (e >= TOT) return;
    int lane = e & 63;
    int tap  = (e >> 6) % 9;
    int gh   = e / (9 * 64);
    int g = gh >> 1, oh = gh & 1;
    int col = lane & 31, hi = lane >> 5;
    const float* wp = W2 + ((size_t)(g * 64 + oh * 32 + col) * 64 + hi * 32) * 9 + tap;
    unsigned int d[8];
#pragma unroll
    for (int i = 0; i < 8; ++i) {
        float f0 = wp[(4 * i + 0) * 9];
        float f1 = wp[(4 * i + 1) * 9];
        float f2 = wp[(4 * i + 2) * 9];
        float f3 = wp[(4 * i + 3) * 9];
        d[i] = pk_fp8(f0, f1) | (pk_fp8(f2, f3) << 16);
    }
    uint4 q0, q1;
    q0.x = d[0]; q0.y = d[2]; q0.z = d[4]; q0.w = d[6];
    q1.x = d[1]; q1.y = d[3]; q1.z = d[5]; q1.w = d[7];
    uint4* op = (uint4*)W2s + (size_t)e * 2;
    op[0] = q0; op[1] = q1;
}

// One block: (batch n, band g, 32x16 strip = two 16x16 tiles). 512 thr, 8 waves.
// r16 pipeline (best measured): conv1(T0) | bar | [conv1(T1) INTERLEAVED with
// conv2(T0)] | epi | bar | outwrite | conv2(T1) | epi | bar | outwrite.
// GELU fully packed (v_pk_f32) in conv1 + epilogue.
__global__ __launch_bounds__(512, 4) void band_kernel(
    const float* __restrict__ x, const float* __restrict__ W1, const float* __restrict__ b1,
    const float* __restrict__ b2, const float* __restrict__ W3, const float* __restrict__ b3,
    const unsigned char* __restrict__ W2s, float* __restrict__ out)
{
    __shared__ float xs[20 * 36];      //  2880 B: halo of the 32x16 strip
    __shared__ uint4 h1s[704 * 5];     // 56320 B: two tile buffers, 352 rows x 80B
    __shared__ float outs[2 * 256];    //  2048 B

    const int tid = threadIdx.x;
    const int txp = blockIdx.x % 6, ty = blockIdx.x / 6;
    const int g = blockIdx.y, n = blockIdx.z;
    const int x0c = txp * 32, y0 = ty * 16;

    const int lane = tid & 63;
    const int wid  = tid >> 6;
    const int w4   = wid & 3;       // row-quarter
    const int oh   = wid >> 2;      // oc-half
    const int hi   = lane >> 5;     // k-half
    const int col  = lane & 31;

    // ---- stage xs strip (20 x 36, halo 2, zero-padded) ----
    const float* xg = x + (size_t)(n * NB + g) * 192 * 192;
    for (int i = tid; i < 720; i += 512) {
        int r = i / 36, c = i - r * 36;
        int gy = y0 + r - 2, gx = x0c + c - 2;
        float v = 0.f;
        if (gy >= 0 && gy < 192 && gx >= 0 && gx < 192) v = xg[gy * 192 + gx];
        xs[i] = v;
    }

    // ---- conv1 A-frag (this wave's oh): k=tap 0..8, k=9 -> b1[oc] ----
    short8 a1;
    {
        const float* wp = W1 + (size_t)(g * 64 + oh * 32 + col) * 9;
        uint4 bw = {0u, 0u, 0u, 0u};
        if (hi == 0) {
            bw.x = cvt_pk_bf16(wp[0], wp[1]);
            bw.y = cvt_pk_bf16(wp[2], wp[3]);
            bw.z = cvt_pk_bf16(wp[4], wp[5]);
            bw.w = cvt_pk_bf16(wp[6], wp[7]);
        } else {
            bw.x = cvt_pk_bf16(wp[8], b1[g * 64 + oh * 32 + col]);
        }
        a1 = __builtin_bit_cast(short8, bw);
    }
    __syncthreads();   // xs ready

    char* h1c = (char*)h1s;
    const int lhalf = (lane >> 4) & 1;
    const int pxl   = lane & 15;
    const int base0 = (4 * w4 + lhalf) * 18 + pxl;
    const int gh = g * 2 + oh;
    const uint4* ap = (const uint4*)W2s + (size_t)gh * 9 * 128 + lane * 2;

    // ---- conv1: one 32-position sub-tile of tile T ----
    auto conv1_iter = [&](int T, int it) {
        const int t = w4 + 4 * it;
        if (t < 11) {
            const int posr = t * 32 + col;             // write row 0..351
            const int pos  = posr < 324 ? posr : 323;  // compute pos (in-bounds)
            int py = pos / 18, px = pos - py * 18;
            int gy = y0 + py - 1, gx = x0c + T * 16 + px - 1;
            unsigned int msk = (gy >= 0 && gy < 192 && gx >= 0 && gx < 192) ? 0xFFFFFFFFu : 0u;

            uint4 bw = {0u, 0u, 0u, 0u};
            if (hi == 0) {
                float xv[8];
#pragma unroll
                for (int j2 = 0; j2 < 8; ++j2)
                    xv[j2] = xs[(py + j2 / 3) * 36 + T * 16 + px + (j2 % 3)];
                bw.x = cvt_pk_bf16(xv[0], xv[1]);
                bw.y = cvt_pk_bf16(xv[2], xv[3]);
                bw.z = cvt_pk_bf16(xv[4], xv[5]);
                bw.w = cvt_pk_bf16(xv[6], xv[7]);
            } else {
                bw.x = cvt_pk_bf16(xs[(py + 2) * 36 + T * 16 + px + 2], 1.0f);
            }
            short8 bfrag = __builtin_bit_cast(short8, bw);

            f32x16 z = {};
            f32x16 c0 = __builtin_amdgcn_mfma_f32_32x32x16_bf16(a1, bfrag, z, 0, 0, 0);

            uint4 st;
#pragma unroll
            for (int s = 0; s < 4; ++s) {
                f32x2 ga = gelu2((f32x2){c0[4 * s + 0], c0[4 * s + 1]});
                f32x2 gb = gelu2((f32x2){c0[4 * s + 2], c0[4 * s + 3]});
                unsigned int d = (pk_fp8(ga[0], ga[1]) | (pk_fp8(gb[0], gb[1]) << 16)) & msk;
                if (s == 0) st.x = d; else if (s == 1) st.y = d;
                else if (s == 2) st.z = d; else st.w = d;
            }
            *(uint4*)(h1c + T * 28160 + posr * 80 + (oh << 5) + (hi << 4)) = st;
        }
    };

    auto acc_init = [&](f32x16& A0v, f32x16& A1v) {
        const float* bp = b2 + g * 64 + oh * 32 + 4 * hi;
#pragma unroll
        for (int s = 0; s < 4; ++s) {
            float4 q = *(const float4*)(bp + 8 * s);
            A0v[4 * s + 0] = q.x; A0v[4 * s + 1] = q.y;
            A0v[4 * s + 2] = q.z; A0v[4 * s + 3] = q.w;
            A1v[4 * s + 0] = q.x; A1v[4 * s + 1] = q.y;
            A1v[4 * s + 2] = q.z; A1v[4 * s + 3] = q.w;
        }
    };

    // ---- conv2: 3 taps of tile T accumulated into A0v/A1v ----
    auto conv2_taps = [&](int T, int tap0, f32x16& A0v, f32x16& A1v) {
#pragma unroll
        for (int tt = 0; tt < 3; ++tt) {
            const int tap = tap0 + tt;
            const int D = (tap / 3) * 18 + (tap % 3);
            const int p0 = base0 + D;
            const int p1 = p0 + 36;
            const char* r0 = h1c + T * 28160 + p0 * 80 + (hi << 5);
            const char* r1 = h1c + T * 28160 + p1 * 80 + (hi << 5);
            uint4 b0a = *(const uint4*)(r0);
            uint4 b0b = *(const uint4*)(r0 + 16);
            uint4 b1a = *(const uint4*)(r1);
            uint4 b1b = *(const uint4*)(r1 + 16);
            uint4 al = ap[tap * 128], ah = ap[tap * 128 + 1];
            int8v A = mk8(al, ah);
            A0v = __builtin_amdgcn_mfma_scale_f32_32x32x64_f8f6f4(
                      A, mk8(b0a, b0b), A0v, 0, 0, 0, 0x7F7F7F7F, 0, 0x7F7F7F7F);
            A1v = __builtin_amdgcn_mfma_scale_f32_32x32x64_f8f6f4(
                      A, mk8(b1a, b1b), A1v, 0, 0, 0, 0x7F7F7F7F, 0, 0x7F7F7F7F);
        }
    };

    auto epilogue = [&](f32x16& A0v, f32x16& A1v) {
        float pa = 0.f, pb = 0.f;
        const float* wp3 = W3 + g * 64 + oh * 32 + 4 * hi;
#pragma unroll
        for (int s = 0; s < 4; ++s) {
            float4 qa = *(const float4*)(wp3 + 8 * s);
            f32x2 gA0 = gelu2((f32x2){A0v[4 * s + 0], A0v[4 * s + 1]});
            f32x2 gA1 = gelu2((f32x2){A0v[4 * s + 2], A0v[4 * s + 3]});
            f32x2 gB0 = gelu2((f32x2){A1v[4 * s + 0], A1v[4 * s + 1]});
            f32x2 gB1 = gelu2((f32x2){A1v[4 * s + 2], A1v[4 * s + 3]});
            pa = __builtin_fmaf(qa.x, gA0[0], pa);
            pa = __builtin_fmaf(qa.y, gA0[1], pa);
            pa = __builtin_fmaf(qa.z, gA1[0], pa);
            pa = __builtin_fmaf(qa.w, gA1[1], pa);
            pb = __builtin_fmaf(qa.x, gB0[0], pb);
            pb = __builtin_fmaf(qa.y, gB0[1], pb);
            pb = __builtin_fmaf(qa.z, gB1[0], pb);
            pb = __builtin_fmaf(qa.w, gB1[1], pb);
        }
        pa += __shfl_xor(pa, 32);
        pb += __shfl_xor(pb, 32);
        if (lane < 32) {
            outs[oh * 256 + w4 * 64 + lane]      = pa;   // NT0
            outs[oh * 256 + w4 * 64 + 32 + lane] = pb;   // NT1
        }
    };

    auto outwrite = [&](int T) {
        if (tid < 256) {
            float v = outs[tid] + outs[256 + tid] + b3[g];
            int py_ = 4 * (tid >> 6) + 2 * ((tid >> 5) & 1) + ((tid >> 4) & 1);
            int px_ = tid & 15;
            out[((size_t)(n * NB + g) * 192 + y0 + py_) * 192 + x0c + T * 16 + px_] = v;
        }
    };

    // ---- pipeline ----
    conv1_iter(0, 0); conv1_iter(0, 1); conv1_iter(0, 2);
    __syncthreads();                                   // h1[0] ready

    f32x16 acc0, acc1;
    acc_init(acc0, acc1);
    conv1_iter(1, 0); conv2_taps(0, 0, acc0, acc1);    // interleaved phase
    conv1_iter(1, 1); conv2_taps(0, 3, acc0, acc1);
    conv1_iter(1, 2); conv2_taps(0, 6, acc0, acc1);
    epilogue(acc0, acc1);
    __syncthreads();                                   // outs(T0) + h1[1] ready
    outwrite(0);
    __syncthreads();                                   // outs consumed

    acc_init(acc0, acc1);
    conv2_taps(1, 0, acc0, acc1);
    conv2_taps(1, 3, acc0, acc1);
    conv2_taps(1, 6, acc0, acc1);
    epilogue(acc0, acc1);
    __syncthreads();
    outwrite(1);
}

// Cross-band fusion, in-place on `out`. 512 threads: waves 0-3 do j=0..30,
// waves 4-7 do j=31..61 for the SAME 256 pixels; halves combine via LDS.
// half forced into SGPR via readfirstlane -> weights stay s_load.
__global__ __launch_bounds__(512) void fuse_kernel(
    const float* __restrict__ x,
    const float* __restrict__ Wf1, const float* __restrict__ bf1,
    const float* __restrict__ Wf2, const float* __restrict__ bf2,
    float* __restrict__ out)
{
    __shared__ float part[256 * 33];   // stride 33 words: bank-clean
    const int tid  = threadIdx.x;
    const int half = __builtin_amdgcn_readfirstlane(tid >> 8);  // SGPR, wave-uniform
    const int pixl = tid & 255;
    int p = blockIdx.x * 256 + pixl;   // 0..73727
    int nn = p / 36864, pix = p - nn * 36864;
    float* basep = out + (size_t)nn * NB * 36864 + pix;
    const float* xb = x + (size_t)nn * NB * 36864 + pix;

    float v[31];
#pragma unroll
    for (int c = 0; c < 31; ++c) v[c] = basep[(size_t)c * 36864];

    float fused[31];
#pragma unroll
    for (int c = 0; c < 31; ++c) fused[c] = 0.f;

    for (int jj = 0; jj < 31; ++jj) {
        int j = half * 31 + jj;        // SGPR arithmetic -> s_load weights
        float a = bf1[j];
#pragma unroll
        for (int c = 0; c < 31; ++c) a = __builtin_fmaf(Wf1[j * 31 + c], v[c], a);
        float fj = gelu_f(a);
#pragma unroll
        for (int c = 0; c < 31; ++c) fused[c] = __builtin_fmaf(Wf2[c * 62 + j], fj, fused[c]);
    }

    if (half == 1) {
#pragma unroll
        for (int c = 0; c < 31; ++c) part[pixl * 33 + c] = fused[c];
    }
    __syncthreads();
    if (half == 0) {
#pragma unroll
        for (int c = 0; c < 31; ++c)
            basep[(size_t)c * 36864] =
                xb[(size_t)c * 36864] + fused[c] + part[pixl * 33 + c] + bf2[c];
    }
}

extern "C" void kernel_launch(void* const* d_in, const int* in_sizes, int n_in,
                              void* d_out, int out_size, void* d_ws, size_t ws_size,
                              hipStream_t stream) {
    const float* x   = (const float*)d_in[0];
    const float* W1  = (const float*)d_in[1];
    const float* b1  = (const float*)d_in[2];
    const float* W2  = (const float*)d_in[3];
    const float* b2  = (const float*)d_in[4];
    const float* W3  = (const float*)d_in[5];
    const float* b3  = (const float*)d_in[6];
    const float* Wf1 = (const float*)d_in[7];
    const float* bf1 = (const float*)d_in[8];
    const float* Wf2 = (const float*)d_in[9];
    const float* bf2 = (const float*)d_in[10];
    float* out = (float*)d_out;
    unsigned char* W2s = (unsigned char*)d_ws;   // 62*9*64*32 = 1,142,784 B

    const int TOT = NB * 2 * 9 * 64;
    hipLaunchKernelGGL(prep_w2, dim3((TOT + 255) / 256), dim3(256), 0, stream, W2, W2s);
    hipLaunchKernelGGL(band_kernel, dim3(72, NB, 2), dim3(512), 0, stream,
                       x, W1, b1, b2, W3, b3, W2s, out);
    hipLaunchKernelGGL(fuse_kernel, dim3(288), dim3(512), 0, stream,
                       x, Wf1, bf1, Wf2, bf2, out);
}

// Round 19
// 157.519 us; speedup vs baseline: 1.0484x; 1.0484x over previous
//
#include <hip/hip_runtime.h>
#include <hip/hip_bf16.h>

#define NB 31
#define PD 64

typedef __attribute__((ext_vector_type(8))) short short8;
typedef __attribute__((ext_vector_type(16))) float f32x16;
typedef __attribute__((ext_vector_type(8))) int int8v;

// 4-inst GELU: x * clamp(0.5 + x*(a + b x^2 + c x^4), 0, 1) via VOP3 clamp
// (scalar form deliberately: packed f32x2 variant regressed via reg-pair
//  alignment pressure in the interleaved phase — r18: 129->141 us)
__device__ __forceinline__ float gelu_f(float x) {
    float y = x * x;
    float p = __builtin_fmaf(y, __builtin_fmaf(y, 0.0042294f, -0.056913f), 0.395442f);
    float phi;
    asm("v_fma_f32 %0, %1, %2, 0.5 clamp" : "=v"(phi) : "v"(x), "v"(p));
    return x * phi;
}

__device__ __forceinline__ unsigned int cvt_pk_bf16(float lo, float hi) {
    unsigned int r;
    asm("v_cvt_pk_bf16_f32 %0, %1, %2" : "=v"(r) : "v"(lo), "v"(hi));
    return r;
}

// 2 floats -> 2 fp8 e4m3 bytes in bits [15:0] (old=0 => high bits 0)
__device__ __forceinline__ unsigned int pk_fp8(float a, float b) {
    return (unsigned int)__builtin_amdgcn_cvt_pk_fp8_f32(a, b, 0, false);
}

__device__ __forceinline__ int8v mk8(uint4 a, uint4 b) {
    int8v r;
    r[0] = a.x; r[1] = a.y; r[2] = a.z; r[3] = a.w;
    r[4] = b.x; r[5] = b.y; r[6] = b.z; r[7] = b.w;
    return r;
}

// W2 (OIHW fp32) -> fp8 MX-MFMA A-fragments for 32x32x64, byte-permuted to
// match h1's layout (r13-verified): A-frag byte bb (0..31) holds ic_local32 =
// 8*((bb>>2)&3) + 4*(bb>>4) + (bb&3); dwords out = {d0,d2,d4,d6, d1,d3,d5,d7}.
// W2s[gh][tap][lane] = 32 bytes; gh = g*2+oh; lane = hi*32 + col (col = oc&31).
__global__ void prep_w2(const float* __restrict__ W2, unsigned char* __restrict__ W2s) {
    int e = blockIdx.x * 256 + threadIdx.x;
    const int TOT = NB * 2 * 9 * 64;
    if (e >= TOT) return;
    int lane = e & 63;
    int tap  = (e >> 6) % 9;
    int gh   = e / (9 * 64);
    int g = gh >> 1, oh = gh & 1;
    int col = lane & 31, hi = lane >> 5;
    const float* wp = W2 + ((size_t)(g * 64 + oh * 32 + col) * 64 + hi * 32) * 9 + tap;
    unsigned int d[8];
#pragma unroll
    for (int i = 0; i < 8; ++i) {
        float f0 = wp[(4 * i + 0) * 9];
        float f1 = wp[(4 * i + 1) * 9];
        float f2 = wp[(4 * i + 2) * 9];
        float f3 = wp[(4 * i + 3) * 9];
        d[i] = pk_fp8(f0, f1) | (pk_fp8(f2, f3) << 16);
    }
    uint4 q0, q1;
    q0.x = d[0]; q0.y = d[2]; q0.z = d[4]; q0.w = d[6];
    q1.x = d[1]; q1.y = d[3]; q1.z = d[5]; q1.w = d[7];
    uint4* op = (uint4*)W2s + (size_t)e * 2;
    op[0] = q0; op[1] = q1;
}

// One block: (batch n, band g, 32x16 strip = two 16x16 tiles). 512 thr, 8 waves.
// r16 pipeline + double-buffered outs (removes the mid barrier; outwrite(T0)
// stores drain under conv2(T1)):
//   conv1(T0) | bar | [conv1(T1) || conv2(T0)] epi(o0) | bar |
//   outwrite(T0,o0); conv2(T1) epi(o1) | bar | outwrite(T1,o1)
__global__ __launch_bounds__(512, 4) void band_kernel(
    const float* __restrict__ x, const float* __restrict__ W1, const float* __restrict__ b1,
    const float* __restrict__ b2, const float* __restrict__ W3, const float* __restrict__ b3,
    const unsigned char* __restrict__ W2s, float* __restrict__ out)
{
    __shared__ float xs[20 * 36];      //  2880 B: halo of the 32x16 strip
    __shared__ uint4 h1s[704 * 5];     // 56320 B: two tile buffers, 352 rows x 80B
    __shared__ float outs[2][512];     //  4096 B: double-buffered

    const int tid = threadIdx.x;
    const int txp = blockIdx.x % 6, ty = blockIdx.x / 6;
    const int g = blockIdx.y, n = blockIdx.z;
    const int x0c = txp * 32, y0 = ty * 16;

    const int lane = tid & 63;
    const int wid  = tid >> 6;
    const int w4   = wid & 3;       // row-quarter
    const int oh   = wid >> 2;      // oc-half
    const int hi   = lane >> 5;     // k-half
    const int col  = lane & 31;

    // ---- stage xs strip (20 x 36, halo 2, zero-padded) ----
    const float* xg = x + (size_t)(n * NB + g) * 192 * 192;
    for (int i = tid; i < 720; i += 512) {
        int r = i / 36, c = i - r * 36;
        int gy = y0 + r - 2, gx = x0c + c - 2;
        float v = 0.f;
        if (gy >= 0 && gy < 192 && gx >= 0 && gx < 192) v = xg[gy * 192 + gx];
        xs[i] = v;
    }

    // ---- conv1 A-frag (this wave's oh): k=tap 0..8, k=9 -> b1[oc] ----
    short8 a1;
    {
        const float* wp = W1 + (size_t)(g * 64 + oh * 32 + col) * 9;
        uint4 bw = {0u, 0u, 0u, 0u};
        if (hi == 0) {
            bw.x = cvt_pk_bf16(wp[0], wp[1]);
            bw.y = cvt_pk_bf16(wp[2], wp[3]);
            bw.z = cvt_pk_bf16(wp[4], wp[5]);
            bw.w = cvt_pk_bf16(wp[6], wp[7]);
        } else {
            bw.x = cvt_pk_bf16(wp[8], b1[g * 64 + oh * 32 + col]);
        }
        a1 = __builtin_bit_cast(short8, bw);
    }
    __syncthreads();   // xs ready

    char* h1c = (char*)h1s;
    const int lhalf = (lane >> 4) & 1;
    const int pxl   = lane & 15;
    const int base0 = (4 * w4 + lhalf) * 18 + pxl;
    const int gh = g * 2 + oh;
    const uint4* ap = (const uint4*)W2s + (size_t)gh * 9 * 128 + lane * 2;

    // ---- conv1: one 32-position sub-tile of tile T ----
    auto conv1_iter = [&](int T, int it) {
        const int t = w4 + 4 * it;
        if (t < 11) {
            const int posr = t * 32 + col;             // write row 0..351
            const int pos  = posr < 324 ? posr : 323;  // compute pos (in-bounds)
            int py = pos / 18, px = pos - py * 18;
            int gy = y0 + py - 1, gx = x0c + T * 16 + px - 1;
            unsigned int msk = (gy >= 0 && gy < 192 && gx >= 0 && gx < 192) ? 0xFFFFFFFFu : 0u;

            uint4 bw = {0u, 0u, 0u, 0u};
            if (hi == 0) {
                float xv[8];
#pragma unroll
                for (int j2 = 0; j2 < 8; ++j2)
                    xv[j2] = xs[(py + j2 / 3) * 36 + T * 16 + px + (j2 % 3)];
                bw.x = cvt_pk_bf16(xv[0], xv[1]);
                bw.y = cvt_pk_bf16(xv[2], xv[3]);
                bw.z = cvt_pk_bf16(xv[4], xv[5]);
                bw.w = cvt_pk_bf16(xv[6], xv[7]);
            } else {
                bw.x = cvt_pk_bf16(xs[(py + 2) * 36 + T * 16 + px + 2], 1.0f);
            }
            short8 bfrag = __builtin_bit_cast(short8, bw);

            f32x16 z = {};
            f32x16 c0 = __builtin_amdgcn_mfma_f32_32x32x16_bf16(a1, bfrag, z, 0, 0, 0);

            uint4 st;
            {
                float u0 = gelu_f(c0[0]),  u1 = gelu_f(c0[1]);
                float u2 = gelu_f(c0[2]),  u3 = gelu_f(c0[3]);
                st.x = (pk_fp8(u0, u1) | (pk_fp8(u2, u3) << 16)) & msk;
            }
            {
                float u0 = gelu_f(c0[4]),  u1 = gelu_f(c0[5]);
                float u2 = gelu_f(c0[6]),  u3 = gelu_f(c0[7]);
                st.y = (pk_fp8(u0, u1) | (pk_fp8(u2, u3) << 16)) & msk;
            }
            {
                float u0 = gelu_f(c0[8]),  u1 = gelu_f(c0[9]);
                float u2 = gelu_f(c0[10]), u3 = gelu_f(c0[11]);
                st.z = (pk_fp8(u0, u1) | (pk_fp8(u2, u3) << 16)) & msk;
            }
            {
                float u0 = gelu_f(c0[12]), u1 = gelu_f(c0[13]);
                float u2 = gelu_f(c0[14]), u3 = gelu_f(c0[15]);
                st.w = (pk_fp8(u0, u1) | (pk_fp8(u2, u3) << 16)) & msk;
            }
            *(uint4*)(h1c + T * 28160 + posr * 80 + (oh << 5) + (hi << 4)) = st;
        }
    };

    auto acc_init = [&](f32x16& A0v, f32x16& A1v) {
        const float* bp = b2 + g * 64 + oh * 32 + 4 * hi;
#pragma unroll
        for (int s = 0; s < 4; ++s) {
            float4 q = *(const float4*)(bp + 8 * s);
            A0v[4 * s + 0] = q.x; A0v[4 * s + 1] = q.y;
            A0v[4 * s + 2] = q.z; A0v[4 * s + 3] = q.w;
            A1v[4 * s + 0] = q.x; A1v[4 * s + 1] = q.y;
            A1v[4 * s + 2] = q.z; A1v[4 * s + 3] = q.w;
        }
    };

    // ---- conv2: 3 taps of tile T accumulated into A0v/A1v ----
    auto conv2_taps = [&](int T, int tap0, f32x16& A0v, f32x16& A1v) {
#pragma unroll
        for (int tt = 0; tt < 3; ++tt) {
            const int tap = tap0 + tt;
            const int D = (tap / 3) * 18 + (tap % 3);
            const int p0 = base0 + D;
            const int p1 = p0 + 36;
            const char* r0 = h1c + T * 28160 + p0 * 80 + (hi << 5);
            const char* r1 = h1c + T * 28160 + p1 * 80 + (hi << 5);
            uint4 b0a = *(const uint4*)(r0);
            uint4 b0b = *(const uint4*)(r0 + 16);
            uint4 b1a = *(const uint4*)(r1);
            uint4 b1b = *(const uint4*)(r1 + 16);
            uint4 al = ap[tap * 128], ah = ap[tap * 128 + 1];
            int8v A = mk8(al, ah);
            A0v = __builtin_amdgcn_mfma_scale_f32_32x32x64_f8f6f4(
                      A, mk8(b0a, b0b), A0v, 0, 0, 0, 0x7F7F7F7F, 0, 0x7F7F7F7F);
            A1v = __builtin_amdgcn_mfma_scale_f32_32x32x64_f8f6f4(
                      A, mk8(b1a, b1b), A1v, 0, 0, 0, 0x7F7F7F7F, 0, 0x7F7F7F7F);
        }
    };

    auto epilogue = [&](int b, f32x16& A0v, f32x16& A1v) {
        float pa = 0.f, pb = 0.f;
        const float* wp3 = W3 + g * 64 + oh * 32 + 4 * hi;
#pragma unroll
        for (int s = 0; s < 4; ++s) {
            float4 qa = *(const float4*)(wp3 + 8 * s);
            pa = __builtin_fmaf(qa.x, gelu_f(A0v[4 * s + 0]), pa);
            pa = __builtin_fmaf(qa.y, gelu_f(A0v[4 * s + 1]), pa);
            pa = __builtin_fmaf(qa.z, gelu_f(A0v[4 * s + 2]), pa);
            pa = __builtin_fmaf(qa.w, gelu_f(A0v[4 * s + 3]), pa);
            pb = __builtin_fmaf(qa.x, gelu_f(A1v[4 * s + 0]), pb);
            pb = __builtin_fmaf(qa.y, gelu_f(A1v[4 * s + 1]), pb);
            pb = __builtin_fmaf(qa.z, gelu_f(A1v[4 * s + 2]), pb);
            pb = __builtin_fmaf(qa.w, gelu_f(A1v[4 * s + 3]), pb);
        }
        pa += __shfl_xor(pa, 32);
        pb += __shfl_xor(pb, 32);
        if (lane < 32) {
            outs[b][oh * 256 + w4 * 64 + lane]      = pa;   // NT0
            outs[b][oh * 256 + w4 * 64 + 32 + lane] = pb;   // NT1
        }
    };

    auto outwrite = [&](int T, int b) {
        if (tid < 256) {
            float v = outs[b][tid] + outs[b][256 + tid] + b3[g];
            int py_ = 4 * (tid >> 6) + 2 * ((tid >> 5) & 1) + ((tid >> 4) & 1);
            int px_ = tid & 15;
            out[((size_t)(n * NB + g) * 192 + y0 + py_) * 192 + x0c + T * 16 + px_] = v;
        }
    };

    // ---- pipeline (3 barriers per block) ----
    conv1_iter(0, 0); conv1_iter(0, 1); conv1_iter(0, 2);
    __syncthreads();                                   // h1[0] ready

    f32x16 acc0, acc1;
    acc_init(acc0, acc1);
    conv1_iter(1, 0); conv2_taps(0, 0, acc0, acc1);    // interleaved phase
    conv1_iter(1, 1); conv2_taps(0, 3, acc0, acc1);
    conv1_iter(1, 2); conv2_taps(0, 6, acc0, acc1);
    epilogue(0, acc0, acc1);
    __syncthreads();                                   // outs[0] + h1[1] ready
    outwrite(0, 0);                                    // stores drain under conv2(T1)

    acc_init(acc0, acc1);
    conv2_taps(1, 0, acc0, acc1);
    conv2_taps(1, 3, acc0, acc1);
    conv2_taps(1, 6, acc0, acc1);
    epilogue(1, acc0, acc1);
    __syncthreads();                                   // outs[1] ready
    outwrite(1, 1);
}

// Cross-band fusion, in-place on `out`. 512 threads: waves 0-3 do j=0..30,
// waves 4-7 do j=31..61 for the SAME 256 pixels; halves combine via LDS.
// half forced into SGPR via readfirstlane -> weights stay s_load.
__global__ __launch_bounds__(512) void fuse_kernel(
    const float* __restrict__ x,
    const float* __restrict__ Wf1, const float* __restrict__ bf1,
    const float* __restrict__ Wf2, const float* __restrict__ bf2,
    float* __restrict__ out)
{
    __shared__ float part[256 * 33];   // stride 33 words: bank-clean
    const int tid  = threadIdx.x;
    const int half = __builtin_amdgcn_readfirstlane(tid >> 8);  // SGPR, wave-uniform
    const int pixl = tid & 255;
    int p = blockIdx.x * 256 + pixl;   // 0..73727
    int nn = p / 36864, pix = p - nn * 36864;
    float* basep = out + (size_t)nn * NB * 36864 + pix;
    const float* xb = x + (size_t)nn * NB * 36864 + pix;

    float v[31];
#pragma unroll
    for (int c = 0; c < 31; ++c) v[c] = basep[(size_t)c * 36864];

    float fused[31];
#pragma unroll
    for (int c = 0; c < 31; ++c) fused[c] = 0.f;

    for (int jj = 0; jj < 31; ++jj) {
        int j = half * 31 + jj;        // SGPR arithmetic -> s_load weights
        float a = bf1[j];
#pragma unroll
        for (int c = 0; c < 31; ++c) a = __builtin_fmaf(Wf1[j * 31 + c], v[c], a);
        float fj = gelu_f(a);
#pragma unroll
        for (int c = 0; c < 31; ++c) fused[c] = __builtin_fmaf(Wf2[c * 62 + j], fj, fused[c]);
    }

    if (half == 1) {
#pragma unroll
        for (int c = 0; c < 31; ++c) part[pixl * 33 + c] = fused[c];
    }
    __syncthreads();
    if (half == 0) {
#pragma unroll
        for (int c = 0; c < 31; ++c)
            basep[(size_t)c * 36864] =
                xb[(size_t)c * 36864] + fused[c] + part[pixl * 33 + c] + bf2[c];
    }
}

extern "C" void kernel_launch(void* const* d_in, const int* in_sizes, int n_in,
                              void* d_out, int out_size, void* d_ws, size_t ws_size,
                              hipStream_t stream) {
    const float* x   = (const float*)d_in[0];
    const float* W1  = (const float*)d_in[1];
    const float* b1  = (const float*)d_in[2];
    const float* W2  = (const float*)d_in[3];
    const float* b2  = (const float*)d_in[4];
    const float* W3  = (const float*)d_in[5];
    const float* b3  = (const float*)d_in[6];
    const float* Wf1 = (const float*)d_in[7];
    const float* bf1 = (const float*)d_in[8];
    const float* Wf2 = (const float*)d_in[9];
    const float* bf2 = (const float*)d_in[10];
    float* out = (float*)d_out;
    unsigned char* W2s = (unsigned char*)d_ws;   // 62*9*64*32 = 1,142,784 B

    const int TOT = NB * 2 * 9 * 64;
    hipLaunchKernelGGL(prep_w2, dim3((TOT + 255) / 256), dim3(256), 0, stream, W2, W2s);
    hipLaunchKernelGGL(band_kernel, dim3(72, NB, 2), dim3(512), 0, stream,
                       x, W1, b1, b2, W3, b3, W2s, out);
    hipLaunchKernelGGL(fuse_kernel, dim3(288), dim3(512), 0, stream,
                       x, Wf1, bf1, Wf2, bf2, out);
}